// Round 11
// baseline (126.237 us; speedup 1.0000x reference)
//
#include <hip/hip_runtime.h>
#include <math.h>

typedef _Float16 h2 __attribute__((ext_vector_type(2)));

#define BB 2
#define NN 6
#define CC 64
#define HH 32
#define WW 88
#define HC 7
#define DG 128
#define HWP (HH*WW)      // 2816
#define GSTR 129
#define OUTCH (CC*HC)    // 448
#define CSTRIDE (HC*DG*DG) // 114688

// ---------------------------------------------------------------------------
// Transpose+downconvert: features (B,N,C,H,W) fp32 -> featT (B,N,H*W,C) fp16.
// LDS-tiled: block = 64 pixels x 64 channels, both sides coalesced.
// ---------------------------------------------------------------------------
__global__ __launch_bounds__(256) void transpose_feat_f16_kernel(
    const float* __restrict__ f, _Float16* __restrict__ ft) {
  __shared__ float lds[64 * 65];   // +1 pad: conflict-free both phases
  int blk = blockIdx.x;
  int bn = blk / 44;
  int pxbase = (blk % 44) * 64;
  int tid = threadIdx.x;
  #pragma unroll
  for (int i = 0; i < 16; ++i) {
    int idx = i * 256 + tid;
    int ch = idx >> 6, px = idx & 63;
    lds[px * 65 + ch] = f[((size_t)bn * CC + ch) * HWP + pxbase + px];
  }
  __syncthreads();
  int px = tid >> 2, cg = (tid & 3) * 16;
  union { h2 hv[8]; int4 v4[2]; } u;
  #pragma unroll
  for (int k = 0; k < 8; ++k) {
    float lo = lds[px * 65 + cg + 2 * k];
    float hi = lds[px * 65 + cg + 2 * k + 1];
    u.hv[k] = (h2){(_Float16)lo, (_Float16)hi};
  }
  int4* dst = (int4*)(ft + ((size_t)bn * HWP + pxbase + px) * CC + cg);
  dst[0] = u.v4[0];
  dst[1] = u.v4[1];
}

// ---------------------------------------------------------------------------
// Main kernel. Channel-split 2-way for occupancy: grid = B*HC*64*2 blocks,
// block = (128,2). Each block computes 32 of the 64 channels for a 128x2
// BEV tile. blk&1 selects the channel half; blk>>1 selects the tile.
// ---------------------------------------------------------------------------
template<bool TRANS>
__global__ __launch_bounds__(256) void oft_main_kernel(
    const float* __restrict__ feats,   // (B,N,C,H,W) fp32
    const _Float16* __restrict__ featT,// (B,N,H*W,C) fp16
    const float* __restrict__ ks, const float* __restrict__ imu,
    const float* __restrict__ prots, const float* __restrict__ ptrans,
    const float* __restrict__ und, const float* __restrict__ grid,
    float* __restrict__ out) {         // (B,448,128,128)
  __shared__ float s_par[NN * 32];
  __shared__ __align__(16) h2 s_beh2[NN * 32];  // all 64 ch per cam

  int blk = blockIdx.x;
  int cs  = blk & 1;                 // channel half: 0 -> ch 0..31, 1 -> 32..63
  int rr  = blk >> 1;
  int b  = rr / (HC * 64);
  int r  = rr % (HC * 64);
  int hc = r / 64;
  int d  = (r % 64) * 2 + threadIdx.y;
  int w  = threadIdx.x;
  int tid = threadIdx.y * 128 + threadIdx.x;
  int chbase = cs * 32;

  // --- per-block camera params (threads 0..5) ---
  if (tid < NN) {
    int n = tid;
    int cam = b * NN + n;
    const float* K = ks + cam * 9;
    const float* M = imu + cam * 12;
    float* P = &s_par[n * 32];
    #pragma unroll
    for (int i = 0; i < 3; ++i)
      #pragma unroll
      for (int k = 0; k < 4; ++k)
        P[i * 4 + k] = K[i*3+0]*M[0*4+k] + K[i*3+1]*M[1*4+k] + K[i*3+2]*M[2*4+k];
    P[12] = K[0]; P[13] = K[4]; P[14] = K[2]; P[15] = K[5];
    const float* u = und + cam * 7;
    #pragma unroll
    for (int i = 0; i < 6; ++i) P[16 + i] = u[i];
    P[23] = u[6];
    const float* R = prots + cam * 9;
    P[24] = R[0]; P[25] = R[1]; P[26] = R[3]; P[27] = R[4];
    const float* T = ptrans + cam * 3;
    P[28] = T[0]; P[29] = T[1];
    float nx = fminf(fmaxf(2.0f * T[0] / 88.0f - 1.0f, -1.f), 1.f);
    float ny = fminf(fmaxf(2.0f * T[1] / 88.0f - 1.0f, -1.f), 1.f);
    bool vis = (nx > -1.f) && (nx < 1.f) && (ny > -1.f) && (ny < 1.f);
    P[30] = vis ? 1.f : 0.f;
    P[31] = 0.f;
  }
  __syncthreads();

  // --- behind-camera constant sample per (cam, ch-pair): 192 entries ---
  if (tid < NN * 32) {
    int n = tid >> 5, m = tid & 31;
    const float* P = &s_par[n * 32];
    float v0 = 0.f, v1 = 0.f;
    if (P[30] != 0.f) {
      float nx = fminf(fmaxf(2.0f * P[28] / 88.0f - 1.0f, -1.f), 1.f);
      float ny = fminf(fmaxf(2.0f * P[29] / 88.0f - 1.0f, -1.f), 1.f);
      float gx = (nx + 1.f) * 0.5f * (float)(WW - 1);
      float gy = (ny + 1.f) * 0.5f * (float)(HH - 1);
      float x0f = floorf(gx), y0f = floorf(gy);
      float wx = gx - x0f, wy = gy - y0f;
      int x0 = (int)fminf(fmaxf(x0f,        0.f), (float)(WW - 1));
      int x1 = (int)fminf(fmaxf(x0f + 1.f,  0.f), (float)(WW - 1));
      int y0 = (int)fminf(fmaxf(y0f,        0.f), (float)(HH - 1));
      int y1 = (int)fminf(fmaxf(y0f + 1.f,  0.f), (float)(HH - 1));
      float w00 = (1.f - wx) * (1.f - wy), w01 = wx * (1.f - wy);
      float w10 = (1.f - wx) * wy,         w11 = wx * wy;
      const float* fb0 = feats + ((size_t)(b * NN + n) * CC + 2*m) * HWP;
      const float* fb1 = fb0 + HWP;
      v0 = fb0[y0*WW+x0]*w00 + fb0[y0*WW+x1]*w01 + fb0[y1*WW+x0]*w10 + fb0[y1*WW+x1]*w11;
      v1 = fb1[y0*WW+x0]*w00 + fb1[y0*WW+x1]*w01 + fb1[y1*WW+x0]*w10 + fb1[y1*WW+x1]*w11;
    }
    s_beh2[tid] = (h2){(_Float16)v0, (_Float16)v1};
  }
  __syncthreads();

  // --- BEV corner point ---
  size_t gidx = (((size_t)b * GSTR + d) * GSTR + w) * 3;
  float px = grid[gidx];
  float py = grid[gidx + 1] + (2.0f - 0.5f * (float)hc);
  float pz = grid[gidx + 2];

  // --- per-camera projection: 0 = zero, 1 = sample, 2 = behind-const ---
  int   mode[NN];
  int   off[NN];
  float fwx[NN], fwy[NN];
  bool any0 = false;
  #pragma unroll
  for (int n = 0; n < NN; ++n) {
    const float* P = &s_par[n * 32];
    float hz = P[8]*px + P[9]*py + P[10]*pz + P[11];
    int md = 0;
    if (hz > 0.f) {
      float hx = P[0]*px + P[1]*py + P[2]*pz + P[3];
      float hy = P[4]*px + P[5]*py + P[6]*pz + P[7];
      float ptx = hx / hz, pty = hy / hz;
      float fx = P[12], fy = P[13], cx = P[14], cy = P[15];
      float xn = (ptx - cx) / fx, yn = (pty - cy) / fy;
      float dx, dy;
      if (P[23] == 1.0f) {   // fisheye
        float r2 = xn*xn + yn*yn;
        float rr2 = sqrtf(r2);
        float th = atanf(rr2);
        float t2 = th*th, t4 = t2*t2;
        float poly = 1.f + P[16]*t2 + P[17]*t4 + P[18]*(t4*t2) + P[21]*(t4*t4);
        float rad = th * poly / rr2;
        dx = xn * rad * fx + cx;
        dy = yn * rad * fy + cy;
      } else {               // pinhole
        float r2 = xn*xn + yn*yn;
        float radial = 1.f + P[16]*r2 + P[17]*r2*r2 + P[18]*r2*r2*r2;
        float xp = xn*radial + 2.f*P[19]*xn*yn + P[20]*(r2 + 2.f*xn*xn);
        float yp = yn*radial + P[19]*(r2 + 2.f*yn*yn) + 2.f*P[20]*xn*yn;
        dx = xp * fx + cx;
        dy = yp * fy + cy;
      }
      float p2x = P[24]*dx + P[25]*dy + P[28];
      float p2y = P[26]*dx + P[27]*dy + P[29];
      float nx = fminf(fmaxf(2.0f * p2x / 88.0f - 1.0f, -1.f), 1.f);
      float ny = fminf(fmaxf(2.0f * p2y / 88.0f - 1.0f, -1.f), 1.f);
      bool visible = (nx > -1.f) && (nx < 1.f) && (ny > -1.f) && (ny < 1.f);
      if (visible) {
        float gx = (nx + 1.f) * 0.5f * (float)(WW - 1);
        float gy = (ny + 1.f) * 0.5f * (float)(HH - 1);
        float x0f = floorf(gx), y0f = floorf(gy);
        fwx[n] = gx - x0f;
        fwy[n] = gy - y0f;
        int x0 = (int)fminf(fmaxf(x0f, 0.f), (float)(WW - 1));
        int y0 = (int)fminf(fmaxf(y0f, 0.f), (float)(HH - 1));
        off[n] = y0 * WW + x0;
        md = 1;
      } else {
        any0 = true;
      }
    } else {
      if (P[30] != 0.f) md = 2; else any0 = true;
    }
    mode[n] = md;
  }

  // --- packed-fp16 accumulator: 16 h2 = 32 channels (this block's half) ---
  h2 acc2[16];
  _Float16 iv = any0 ? (_Float16)0.f : (_Float16)(-INFINITY);
  h2 inith = (h2){iv, iv};
  #pragma unroll
  for (int m = 0; m < 16; ++m) acc2[m] = inith;

  #pragma unroll
  for (int n = 0; n < NN; ++n) {
    if (mode[n] == 1) {
      float wxv = fwx[n], wyv = fwy[n];
      _Float16 hw00 = (_Float16)((1.f - wxv) * (1.f - wyv));
      _Float16 hw01 = (_Float16)(wxv * (1.f - wyv));
      _Float16 hw10 = (_Float16)((1.f - wxv) * wyv);
      _Float16 hw11 = (_Float16)(wxv * wyv);
      h2 w00h = (h2){hw00, hw00}, w01h = (h2){hw01, hw01};
      h2 w10h = (h2){hw10, hw10}, w11h = (h2){hw11, hw11};
      if (TRANS) {
        // base: this block's 64B half of the 128B pixel record (64B aligned)
        const int4* t00 = (const int4*)(featT +
            ((size_t)(b*NN+n)*HWP + off[n]) * CC + chbase);
        const int4* t01 = t00 + (CC/8);            // x+1: +128B record
        const int4* t10 = t00 + (size_t)WW*(CC/8); // y+1: +1 image row
        const int4* t11 = t10 + (CC/8);
        #pragma unroll
        for (int j = 0; j < 4; ++j) {
          int4 A = t00[j], B4 = t01[j], C4 = t10[j], D4 = t11[j];
          const h2* av = (const h2*)&A;
          const h2* bv = (const h2*)&B4;
          const h2* cv = (const h2*)&C4;
          const h2* dv = (const h2*)&D4;
          #pragma unroll
          for (int k = 0; k < 4; ++k) {
            h2 v = av[k]*w00h + bv[k]*w01h + cv[k]*w10h + dv[k]*w11h;
            acc2[j*4+k] = __builtin_elementwise_max(acc2[j*4+k], v);
          }
        }
      } else {
        float w00 = (1.f - wxv) * (1.f - wyv), w01 = wxv * (1.f - wyv);
        float w10 = (1.f - wxv) * wyv,         w11 = wxv * wyv;
        const float* fb = feats + ((size_t)(b*NN+n) * CC + chbase) * HWP + off[n];
        #pragma unroll
        for (int m = 0; m < 16; ++m) {
          const float* p0 = fb + (size_t)(2*m) * HWP;
          const float* p1 = p0 + HWP;
          float v0 = p0[0]*w00 + p0[1]*w01 + p0[WW]*w10 + p0[WW+1]*w11;
          float v1 = p1[0]*w00 + p1[1]*w01 + p1[WW]*w10 + p1[WW+1]*w11;
          acc2[m] = __builtin_elementwise_max(acc2[m],
                        (h2){(_Float16)v0, (_Float16)v1});
        }
      }
    } else if (mode[n] == 2) {
      const h2* bp = &s_beh2[n * 32 + cs * 16];
      #pragma unroll
      for (int m = 0; m < 16; ++m)
        acc2[m] = __builtin_elementwise_max(acc2[m], bp[m]);
    }
  }

  // --- write out[b, c*7+hc, d, w], c = chbase+2m / chbase+2m+1 ---
  float* op = out + (((size_t)b * OUTCH + hc) * DG + d) * DG + w
            + (size_t)chbase * CSTRIDE;
  #pragma unroll
  for (int m = 0; m < 16; ++m) {
    op[(size_t)(2*m)   * CSTRIDE] = (float)acc2[m].x;
    op[(size_t)(2*m+1) * CSTRIDE] = (float)acc2[m].y;
  }
}

extern "C" void kernel_launch(void* const* d_in, const int* in_sizes, int n_in,
                              void* d_out, int out_size, void* d_ws, size_t ws_size,
                              hipStream_t stream) {
  const float* feats  = (const float*)d_in[0];
  const float* ks     = (const float*)d_in[1];
  const float* imu    = (const float*)d_in[2];
  const float* prots  = (const float*)d_in[3];
  const float* ptrans = (const float*)d_in[4];
  const float* und    = (const float*)d_in[5];
  const float* grid   = (const float*)d_in[6];
  float* out = (float*)d_out;

  size_t featT_bytes = (size_t)BB * NN * HWP * CC * sizeof(_Float16);
  bool trans = (d_ws != nullptr) && (ws_size >= featT_bytes);
  _Float16* featT = (_Float16*)d_ws;

  dim3 mblock(128, 2);
  dim3 mgrid(BB * HC * 64 * 2);   // 1792 blocks = 7.0 per CU

  if (trans) {
    transpose_feat_f16_kernel<<<BB * NN * 44, 256, 0, stream>>>(feats, featT);
    oft_main_kernel<true><<<mgrid, mblock, 0, stream>>>(
        feats, featT, ks, imu, prots, ptrans, und, grid, out);
  } else {
    oft_main_kernel<false><<<mgrid, mblock, 0, stream>>>(
        feats, featT, ks, imu, prots, ptrans, und, grid, out);
  }
}